// Round 1
// baseline (399.830 us; speedup 1.0000x reference)
//
#include <hip/hip_runtime.h>
#include <stdint.h>

typedef unsigned short u16;
typedef __attribute__((ext_vector_type(8))) short short8;
typedef __attribute__((ext_vector_type(8))) u16 ushort8;
typedef __attribute__((ext_vector_type(4))) float floatx4;

__device__ __forceinline__ u16 f2bf(float f) {
  union { float f; unsigned u; } c; c.f = f;
  unsigned u = c.u;
  return (u16)((u + 0x7fffu + ((u >> 16) & 1u)) >> 16);
}

// async global->LDS, 16 bytes per lane. LDS dest is wave-uniform base + lane*16,
// so per-lane l must be laid out lane-contiguous (it is: l = &lds[tid*8]).
__device__ __forceinline__ void async16(const u16* g, u16* l) {
  auto* gp = reinterpret_cast<const __attribute__((address_space(1))) uint32_t*>(
      reinterpret_cast<uintptr_t>(g));
  auto* lp = reinterpret_cast<__attribute__((address_space(3))) uint32_t*>(
      reinterpret_cast<uintptr_t>(l));
  __builtin_amdgcn_global_load_lds(gp, lp, 16, 0, 0);
}

// ---------------------------------------------------------------------------
// C = A * B^T.  A: [M][K] row-major bf16 (lda), B: [N][K] row-major bf16 (ldb).
// OUT_BF16: 0 -> fp32 C, 1 -> bf16 C.  scale applied in epilogue.
// causal_skip: skip tiles with n0 >= m0+128 (strictly above diagonal).
// causal_klimit: clamp K-loop to k < m0+128 (A columns beyond are zero).
// ---------------------------------------------------------------------------
template <int OUT_BF16>
__global__ __launch_bounds__(256) void gemm_bt(
    const u16* __restrict__ A, const u16* __restrict__ B, void* __restrict__ Cv,
    int M, int N, int K, int lda, int ldb, int ldc,
    long long sA, long long sB, long long sC,
    float scale, int causal_skip, int causal_klimit) {
  const int m0 = blockIdx.x * 128;
  const int n0 = blockIdx.y * 128;
  if (causal_skip && n0 >= m0 + 128) return;
  A += (size_t)blockIdx.z * sA;
  B += (size_t)blockIdx.z * sB;

  __shared__ u16 As[128 * 32];
  __shared__ u16 Bs[128 * 32];

  const int tid = threadIdx.x;
  const int lane = tid & 63;
  const int wid = tid >> 6;
  const int wm = (wid & 1) * 64;
  const int wn = (wid >> 1) * 64;
  const int fr = lane & 15;   // m/n index within 16x16 frag
  const int fq = lane >> 4;   // k-block selector (k = fq*8 + j)

  floatx4 acc[4][4] = {};

  int kt_end = K >> 5;
  if (causal_klimit) {
    int lim = (m0 >> 5) + 4;
    if (lim < kt_end) kt_end = lim;
  }

  const int rowi = tid >> 2;  // 0..63
  const int segi = tid & 3;   // 16B segment within 64B row
  const u16* gA = A + (size_t)(m0 + rowi) * lda + segi * 8;
  const u16* gB = B + (size_t)(n0 + rowi) * ldb + segi * 8;
  u16* lA = &As[tid * 8];
  u16* lB = &Bs[tid * 8];

  for (int kt = 0; kt < kt_end; ++kt) {
    const int k0 = kt << 5;
    async16(gA + k0, lA);
    async16(gA + k0 + (size_t)64 * lda, lA + 2048);
    async16(gB + k0, lB);
    async16(gB + k0 + (size_t)64 * ldb, lB + 2048);
    __builtin_amdgcn_s_waitcnt(0);
    __syncthreads();

    short8 av[4], bv[4];
#pragma unroll
    for (int i = 0; i < 4; ++i)
      av[i] = *(const short8*)&As[(wm + i * 16 + fr) * 32 + fq * 8];
#pragma unroll
    for (int j = 0; j < 4; ++j)
      bv[j] = *(const short8*)&Bs[(wn + j * 16 + fr) * 32 + fq * 8];

#pragma unroll
    for (int i = 0; i < 4; ++i)
#pragma unroll
      for (int j = 0; j < 4; ++j)
        acc[i][j] = __builtin_amdgcn_mfma_f32_16x16x32_bf16(av[i], bv[j],
                                                            acc[i][j], 0, 0, 0);
    __syncthreads();
  }

  // Epilogue. C/D layout: col = lane&15 (=fr), row = fq*4 + reg.
  if (OUT_BF16) {
    u16* C = (u16*)Cv + (size_t)blockIdx.z * sC;
#pragma unroll
    for (int i = 0; i < 4; ++i) {
      const int m = m0 + wm + i * 16 + fq * 4;
#pragma unroll
      for (int j = 0; j < 4; ++j) {
        const int n = n0 + wn + j * 16 + fr;
#pragma unroll
        for (int r = 0; r < 4; ++r)
          C[(size_t)(m + r) * ldc + n] = f2bf(acc[i][j][r] * scale);
      }
    }
  } else {
    float* C = (float*)Cv + (size_t)blockIdx.z * sC;
#pragma unroll
    for (int i = 0; i < 4; ++i) {
      const int m = m0 + wm + i * 16 + fq * 4;
#pragma unroll
      for (int j = 0; j < 4; ++j) {
        const int n = n0 + wn + j * 16 + fr;
#pragma unroll
        for (int r = 0; r < 4; ++r)
          C[(size_t)(m + r) * ldc + n] = acc[i][j][r] * scale;
      }
    }
  }
}

// fp32 -> bf16 cast, 8 elems/thread
__global__ __launch_bounds__(256) void cast8(const float* __restrict__ in,
                                             u16* __restrict__ out, int n8) {
  int i = blockIdx.x * 256 + threadIdx.x;
  if (i >= n8) return;
  floatx4 a = ((const floatx4*)in)[i * 2];
  floatx4 b = ((const floatx4*)in)[i * 2 + 1];
  ushort8 o;
#pragma unroll
  for (int j = 0; j < 4; ++j) { o[j] = f2bf(a[j]); o[4 + j] = f2bf(b[j]); }
  ((ushort8*)out)[i] = o;
}

// fp32 [R][C] -> bf16 [C][R] (transpose + cast), 64x64 tiles
__global__ __launch_bounds__(256) void transpose_cast64(
    const float* __restrict__ in, u16* __restrict__ out, int R, int C) {
  __shared__ u16 tile[64][72];
  const int r0 = blockIdx.x * 64;
  const int c0 = blockIdx.y * 64;
  const int tid = threadIdx.x;
#pragma unroll
  for (int rnd = 0; rnd < 2; ++rnd) {
    int e = rnd * 256 + tid;
    int rr = e >> 3, seg = e & 7;
    const float* p = &in[(size_t)(r0 + rr) * C + c0 + seg * 8];
    floatx4 a = *(const floatx4*)p;
    floatx4 b = *(const floatx4*)(p + 4);
    u16* tp = &tile[rr][seg * 8];
#pragma unroll
    for (int j = 0; j < 4; ++j) { tp[j] = f2bf(a[j]); tp[4 + j] = f2bf(b[j]); }
  }
  __syncthreads();
#pragma unroll
  for (int rnd = 0; rnd < 2; ++rnd) {
    int e = rnd * 256 + tid;
    int cc = e >> 3, rseg = e & 7;
    ushort8 tv;
#pragma unroll
    for (int j = 0; j < 8; ++j) tv[j] = tile[rseg * 8 + j][cc];
    *(ushort8*)&out[(size_t)(c0 + cc) * R + r0 + rseg * 8] = tv;
  }
}

// bf16 [R][C] -> bf16 [C][R] per batch z
__global__ __launch_bounds__(256) void transpose64(
    const u16* __restrict__ in, u16* __restrict__ out, int R, int C) {
  __shared__ u16 tile[64][72];
  const size_t boff = (size_t)blockIdx.z * R * C;
  const int r0 = blockIdx.x * 64;
  const int c0 = blockIdx.y * 64;
  const int tid = threadIdx.x;
#pragma unroll
  for (int rnd = 0; rnd < 2; ++rnd) {
    int e = rnd * 256 + tid;
    int rr = e >> 3, seg = e & 7;
    ushort8 v = *(const ushort8*)&in[boff + (size_t)(r0 + rr) * C + c0 + seg * 8];
    *(ushort8*)&tile[rr][seg * 8] = v;
  }
  __syncthreads();
#pragma unroll
  for (int rnd = 0; rnd < 2; ++rnd) {
    int e = rnd * 256 + tid;
    int cc = e >> 3, rseg = e & 7;
    ushort8 tv;
#pragma unroll
    for (int j = 0; j < 8; ++j) tv[j] = tile[rseg * 8 + j][cc];
    *(ushort8*)&out[boff + (size_t)(c0 + cc) * R + r0 + rseg * 8] = tv;
  }
}

// Causal row softmax, fp32 S row -> bf16 P row written IN PLACE over the same
// buffer (P row stride = 2*T u16 elems == S row stride in bytes). Safe: all
// reads of the row happen before the first write (vals cached in registers).
__global__ __launch_bounds__(256) void softmax_causal(
    const float* __restrict__ S, u16* __restrict__ P, int T) {
  const int row = blockIdx.x;
  const int t = row & (T - 1);
  const int len = t + 1;
  const float* srow = S + (size_t)row * T;
  u16* prow = P + (size_t)row * 2 * T;
  const int tid = threadIdx.x;

  float vals[8];
  int cnt = 0;
  float mx = -1e30f;
  for (int i = tid; i < len; i += 256) {
    float v = srow[i];
    vals[cnt++] = v;
    mx = fmaxf(mx, v);
  }
  __shared__ float red[4];
#pragma unroll
  for (int o = 32; o > 0; o >>= 1) mx = fmaxf(mx, __shfl_down(mx, o, 64));
  if ((tid & 63) == 0) red[tid >> 6] = mx;
  __syncthreads();
  mx = fmaxf(fmaxf(red[0], red[1]), fmaxf(red[2], red[3]));
  __syncthreads();

  float sum = 0.f;
  for (int c = 0; c < cnt; ++c) {
    vals[c] = __expf(vals[c] - mx);
    sum += vals[c];
  }
#pragma unroll
  for (int o = 32; o > 0; o >>= 1) sum += __shfl_down(sum, o, 64);
  if ((tid & 63) == 0) red[tid >> 6] = sum;
  __syncthreads();
  sum = red[0] + red[1] + red[2] + red[3];
  const float inv = 1.f / sum;

  int c = 0;
  for (int i = tid; i < len; i += 256) prow[i] = f2bf(vals[c++] * inv);
  for (int i = tid; i < T; i += 256)
    if (i >= len) prow[i] = 0;
}

extern "C" void kernel_launch(void* const* d_in, const int* in_sizes, int n_in,
                              void* d_out, int out_size, void* d_ws,
                              size_t ws_size, hipStream_t stream) {
  (void)in_sizes; (void)n_in; (void)out_size; (void)ws_size;
  const float* k  = (const float*)d_in[1];
  const float* q  = (const float*)d_in[2];
  const float* v  = (const float*)d_in[3];
  const float* Wk = (const float*)d_in[4];
  const float* Wq = (const float*)d_in[5];
  float* out = (float*)d_out;

  const int B = 4, T = 2048, C = 1024, H = 1024;
  const int M = B * T;  // 8192

  char* ws = (char*)d_ws;
  size_t off = 0;
  auto alloc = [&](size_t bytes) {
    void* p = ws + off;
    off += (bytes + 255) & ~(size_t)255;
    return p;
  };
  u16* qb  = (u16*)alloc((size_t)M * C * 2);  // reused as vp after step 2
  u16* kb  = (u16*)alloc((size_t)M * C * 2);  // reused as vpT after step 3
  u16* vb  = (u16*)alloc((size_t)M * C * 2);
  u16* WqT = (u16*)alloc((size_t)H * C * 2);
  u16* WkT = (u16*)alloc((size_t)H * C * 2);
  u16* qp  = (u16*)alloc((size_t)M * H * 2);
  u16* kp  = (u16*)alloc((size_t)M * H * 2);
  float* Sf = (float*)alloc((size_t)B * T * T * 4);  // P aliases this (bf16)

  const int n8 = M * C / 8;
  cast8<<<dim3(n8 / 256), 256, 0, stream>>>(q, qb, n8);
  cast8<<<dim3(n8 / 256), 256, 0, stream>>>(k, kb, n8);
  cast8<<<dim3(n8 / 256), 256, 0, stream>>>(v, vb, n8);
  transpose_cast64<<<dim3(C / 64, H / 64), 256, 0, stream>>>(Wq, WqT, C, H);
  transpose_cast64<<<dim3(C / 64, H / 64), 256, 0, stream>>>(Wk, WkT, C, H);

  // projections: qp = q*Wq, kp = k*Wk, vp = v*Wq (reference quirk)
  gemm_bt<1><<<dim3(M / 128, H / 128, 1), 256, 0, stream>>>(
      qb, WqT, qp, M, H, C, C, C, H, 0, 0, 0, 1.f, 0, 0);
  gemm_bt<1><<<dim3(M / 128, H / 128, 1), 256, 0, stream>>>(
      kb, WkT, kp, M, H, C, C, C, H, 0, 0, 0, 1.f, 0, 0);
  gemm_bt<1><<<dim3(M / 128, H / 128, 1), 256, 0, stream>>>(
      vb, WqT, qb, M, H, C, C, C, H, 0, 0, 0, 1.f, 0, 0);
  // vp [B][T][H] -> vpT [B][H][T]
  transpose64<<<dim3(T / 64, H / 64, B), 256, 0, stream>>>(qb, kb, T, H);

  // S = qp*kp^T / 32, causal tile skip
  gemm_bt<0><<<dim3(T / 128, T / 128, B), 256, 0, stream>>>(
      qp, kp, Sf, T, T, C, C, C, T,
      (long long)T * C, (long long)T * C, (long long)T * T, 0.03125f, 1, 0);

  softmax_causal<<<dim3(B * T), 256, 0, stream>>>(Sf, (u16*)Sf, T);

  // out = P * vpT^T  (K limited to m0+128 since P is zero above diagonal)
  gemm_bt<0><<<dim3(T / 128, H / 128, B), 256, 0, stream>>>(
      (const u16*)Sf, kb, out, T, H, T, 2 * T, T, H,
      (long long)2 * T * T, (long long)H * T, (long long)T * H, 1.f, 0, 1);
}

// Round 2
// 362.520 us; speedup vs baseline: 1.1029x; 1.1029x over previous
//
#include <hip/hip_runtime.h>
#include <stdint.h>

typedef unsigned short u16;
typedef __attribute__((ext_vector_type(8))) short short8;
typedef __attribute__((ext_vector_type(8))) u16 ushort8;
typedef __attribute__((ext_vector_type(4))) float floatx4;

__device__ __forceinline__ u16 f2bf(float f) {
  union { float f; unsigned u; } c; c.f = f;
  unsigned u = c.u;
  return (u16)((u + 0x7fffu + ((u >> 16) & 1u)) >> 16);
}
__device__ __forceinline__ float bf2f(u16 h) {
  union { unsigned u; float f; } c; c.u = (unsigned)h << 16;
  return c.f;
}

// async global->LDS, 16 bytes per lane; LDS dest must be lane-contiguous.
__device__ __forceinline__ void async16(const u16* g, u16* l) {
  auto* gp = reinterpret_cast<const __attribute__((address_space(1))) uint32_t*>(
      reinterpret_cast<uintptr_t>(g));
  auto* lp = reinterpret_cast<__attribute__((address_space(3))) uint32_t*>(
      reinterpret_cast<uintptr_t>(l));
  __builtin_amdgcn_global_load_lds(gp, lp, 16, 0, 0);
}

// ---------------------------------------------------------------------------
// C = A * B^T.  A: [M][K] bf16 row-major (lda), B: [N][K] bf16 row-major (ldb).
// Block tile: 128 x BN (BN in {128,256}), 512 threads = 8 waves (2x4),
// wave tile 64 x (BN/4).  BN=256 -> per-wave 64x64 (m97 shape, 16 MFMA : 8 ds).
// causal_skip: skip tiles fully above diagonal (BN=128 only).
// causal_klimit: clamp K to m0+128 (A cols beyond are zero).
// ---------------------------------------------------------------------------
template <int BN, int OUT_BF16>
__global__ __launch_bounds__(512) void gemm_bt(
    const u16* __restrict__ A, const u16* __restrict__ B, void* __restrict__ Cv,
    int K, int lda, int ldb, int ldc,
    long long sA, long long sB, long long sC,
    float scale, int causal_skip, int causal_klimit) {
  const int m0 = blockIdx.x * 128;
  const int n0 = blockIdx.y * BN;
  if (causal_skip && n0 >= m0 + 128) return;
  A += (size_t)blockIdx.z * sA;
  B += (size_t)blockIdx.z * sB;

  __shared__ u16 As[128 * 32];
  __shared__ u16 Bs[BN * 32];

  const int tid = threadIdx.x;
  const int lane = tid & 63;
  const int wid = tid >> 6;          // 0..7
  constexpr int WN = BN / 4;         // 32 or 64
  constexpr int FN = WN / 16;        // 2 or 4
  const int wm = (wid & 1) * 64;
  const int wn = (wid >> 1) * WN;
  const int fr = lane & 15;          // m/n within 16x16 frag
  const int fq = lane >> 4;          // k-block selector

  floatx4 acc[4][FN] = {};

  int kt_end = K >> 5;
  if (causal_klimit) {
    int lim = (m0 >> 5) + 4;
    if (lim < kt_end) kt_end = lim;
  }

  const int rowi = tid >> 2;  // 0..127
  const int segi = tid & 3;   // 16B segment within 64B row
  const u16* gA = A + (size_t)(m0 + rowi) * lda + segi * 8;
  const u16* gB = B + (size_t)(n0 + rowi) * ldb + segi * 8;
  u16* lA = &As[tid * 8];
  u16* lB = &Bs[tid * 8];

  for (int kt = 0; kt < kt_end; ++kt) {
    const int k0 = kt << 5;
    async16(gA + k0, lA);
    async16(gB + k0, lB);
    if (BN == 256) async16(gB + k0 + (size_t)128 * ldb, lB + 4096);
    __builtin_amdgcn_s_waitcnt(0);
    __syncthreads();

    short8 av[4], bv[FN];
#pragma unroll
    for (int i = 0; i < 4; ++i)
      av[i] = *(const short8*)&As[(wm + i * 16 + fr) * 32 + fq * 8];
#pragma unroll
    for (int j = 0; j < FN; ++j)
      bv[j] = *(const short8*)&Bs[(wn + j * 16 + fr) * 32 + fq * 8];

#pragma unroll
    for (int i = 0; i < 4; ++i)
#pragma unroll
      for (int j = 0; j < FN; ++j)
        acc[i][j] = __builtin_amdgcn_mfma_f32_16x16x32_bf16(av[i], bv[j],
                                                            acc[i][j], 0, 0, 0);
    __syncthreads();
  }

  // Epilogue. C/D layout: col = lane&15 (=fr), row = fq*4 + reg.
  if (OUT_BF16) {
    u16* C = (u16*)Cv + (size_t)blockIdx.z * sC;
#pragma unroll
    for (int i = 0; i < 4; ++i) {
      const int m = m0 + wm + i * 16 + fq * 4;
#pragma unroll
      for (int j = 0; j < FN; ++j) {
        const int n = n0 + wn + j * 16 + fr;
#pragma unroll
        for (int r = 0; r < 4; ++r)
          C[(size_t)(m + r) * ldc + n] = f2bf(acc[i][j][r] * scale);
      }
    }
  } else {
    float* C = (float*)Cv + (size_t)blockIdx.z * sC;
#pragma unroll
    for (int i = 0; i < 4; ++i) {
      const int m = m0 + wm + i * 16 + fq * 4;
#pragma unroll
      for (int j = 0; j < FN; ++j) {
        const int n = n0 + wn + j * 16 + fr;
#pragma unroll
        for (int r = 0; r < 4; ++r)
          C[(size_t)(m + r) * ldc + n] = acc[i][j][r] * scale;
      }
    }
  }
}

// fp32 -> bf16 cast for q,k,v in one dispatch (blockIdx.y selects source)
__global__ __launch_bounds__(256) void cast3(
    const float* __restrict__ q, const float* __restrict__ k,
    const float* __restrict__ v, u16* __restrict__ out, int n8) {
  int i = blockIdx.x * 256 + threadIdx.x;
  if (i >= n8) return;
  const float* src = blockIdx.y == 0 ? q : (blockIdx.y == 1 ? k : v);
  u16* dst = out + (size_t)blockIdx.y * n8 * 8;
  floatx4 a = ((const floatx4*)src)[i * 2];
  floatx4 b = ((const floatx4*)src)[i * 2 + 1];
  ushort8 o;
#pragma unroll
  for (int j = 0; j < 4; ++j) { o[j] = f2bf(a[j]); o[4 + j] = f2bf(b[j]); }
  ((ushort8*)dst)[i] = o;
}

// fp32 [R][C] -> bf16 [C][R] (transpose + cast), 64x64 tiles
__global__ __launch_bounds__(256) void transpose_cast64(
    const float* __restrict__ in, u16* __restrict__ out, int R, int C) {
  __shared__ u16 tile[64][72];
  const int r0 = blockIdx.x * 64;
  const int c0 = blockIdx.y * 64;
  const int tid = threadIdx.x;
#pragma unroll
  for (int rnd = 0; rnd < 2; ++rnd) {
    int e = rnd * 256 + tid;
    int rr = e >> 3, seg = e & 7;
    const float* p = &in[(size_t)(r0 + rr) * C + c0 + seg * 8];
    floatx4 a = *(const floatx4*)p;
    floatx4 b = *(const floatx4*)(p + 4);
    u16* tp = &tile[rr][seg * 8];
#pragma unroll
    for (int j = 0; j < 4; ++j) { tp[j] = f2bf(a[j]); tp[4 + j] = f2bf(b[j]); }
  }
  __syncthreads();
#pragma unroll
  for (int rnd = 0; rnd < 2; ++rnd) {
    int e = rnd * 256 + tid;
    int cc = e >> 3, rseg = e & 7;
    ushort8 tv;
#pragma unroll
    for (int j = 0; j < 8; ++j) tv[j] = tile[rseg * 8 + j][cc];
    *(ushort8*)&out[(size_t)(c0 + cc) * R + r0 + rseg * 8] = tv;
  }
}

// bf16 [R][C] -> bf16 [C][R] per batch z
__global__ __launch_bounds__(256) void transpose64(
    const u16* __restrict__ in, u16* __restrict__ out, int R, int C) {
  __shared__ u16 tile[64][72];
  const size_t boff = (size_t)blockIdx.z * R * C;
  const int r0 = blockIdx.x * 64;
  const int c0 = blockIdx.y * 64;
  const int tid = threadIdx.x;
#pragma unroll
  for (int rnd = 0; rnd < 2; ++rnd) {
    int e = rnd * 256 + tid;
    int rr = e >> 3, seg = e & 7;
    ushort8 v = *(const ushort8*)&in[boff + (size_t)(r0 + rr) * C + c0 + seg * 8];
    *(ushort8*)&tile[rr][seg * 8] = v;
  }
  __syncthreads();
#pragma unroll
  for (int rnd = 0; rnd < 2; ++rnd) {
    int e = rnd * 256 + tid;
    int cc = e >> 3, rseg = e & 7;
    ushort8 tv;
#pragma unroll
    for (int j = 0; j < 8; ++j) tv[j] = tile[rseg * 8 + j][cc];
    *(ushort8*)&out[boff + (size_t)(c0 + cc) * R + r0 + rseg * 8] = tv;
  }
}

// Causal row softmax, bf16 in-place. All reads complete before the sum-barrier;
// writes only after it -> in-place safe within the block's own row.
__global__ __launch_bounds__(256) void softmax_causal(u16* __restrict__ S,
                                                      int T) {
  const int row = blockIdx.x;
  const int t = row & (T - 1);
  const int len = t + 1;
  u16* srow = S + (size_t)row * T;
  const int tid = threadIdx.x;

  float vals[8];
  int cnt = 0;
  float mx = -1e30f;
  for (int i = tid; i < len; i += 256) {
    float v = bf2f(srow[i]);
    vals[cnt++] = v;
    mx = fmaxf(mx, v);
  }
  __shared__ float red[4];
#pragma unroll
  for (int o = 32; o > 0; o >>= 1) mx = fmaxf(mx, __shfl_down(mx, o, 64));
  if ((tid & 63) == 0) red[tid >> 6] = mx;
  __syncthreads();
  mx = fmaxf(fmaxf(red[0], red[1]), fmaxf(red[2], red[3]));
  __syncthreads();

  float sum = 0.f;
  for (int c = 0; c < cnt; ++c) {
    vals[c] = __expf(vals[c] - mx);
    sum += vals[c];
  }
#pragma unroll
  for (int o = 32; o > 0; o >>= 1) sum += __shfl_down(sum, o, 64);
  if ((tid & 63) == 0) red[tid >> 6] = sum;
  __syncthreads();
  sum = red[0] + red[1] + red[2] + red[3];
  const float inv = 1.f / sum;

  int c = 0;
  for (int i = tid; i < len; i += 256) srow[i] = f2bf(vals[c++] * inv);
  for (int i = tid; i < T; i += 256)
    if (i >= len) srow[i] = 0;
}

extern "C" void kernel_launch(void* const* d_in, const int* in_sizes, int n_in,
                              void* d_out, int out_size, void* d_ws,
                              size_t ws_size, hipStream_t stream) {
  (void)in_sizes; (void)n_in; (void)out_size; (void)ws_size;
  const float* k  = (const float*)d_in[1];
  const float* q  = (const float*)d_in[2];
  const float* v  = (const float*)d_in[3];
  const float* Wk = (const float*)d_in[4];
  const float* Wq = (const float*)d_in[5];
  float* out = (float*)d_out;

  const int B = 4, T = 2048, C = 1024, H = 1024;
  const int M = B * T;  // 8192
  const size_t MC = (size_t)M * C, CH = (size_t)C * H, MH = (size_t)M * H;

  u16* qkv  = (u16*)d_ws;        // 3 slots [M][C] bf16 (q,k,v)        48 MB
  u16* WT   = qkv + 3 * MC;      // 3 slots [H][C] bf16 (Wq,Wk,Wq)      6 MB
  u16* qkvp = WT + 3 * CH;       // 3 slots [M][H] bf16 (qp,kp,vp)     48 MB
  u16* Sb   = qkvp + 3 * MH;     // [B][T][T] bf16 (S, then P)       33.5 MB
  u16* vpT  = qkv;               // reuse: [B][H][T] bf16 after projections

  const int n8 = (int)(MC / 8);
  cast3<<<dim3(n8 / 256, 3), 256, 0, stream>>>(q, k, v, qkv, n8);
  transpose_cast64<<<dim3(C / 64, H / 64), 256, 0, stream>>>(Wq, WT, C, H);
  transpose_cast64<<<dim3(C / 64, H / 64), 256, 0, stream>>>(Wk, WT + CH, C, H);
  transpose_cast64<<<dim3(C / 64, H / 64), 256, 0, stream>>>(Wq, WT + 2 * CH, C, H);

  // qp = q*Wq, kp = k*Wk, vp = v*Wq  (one batched dispatch, z=0..2)
  gemm_bt<256, 1><<<dim3(M / 128, H / 256, 3), 512, 0, stream>>>(
      qkv, WT, qkvp, C, C, C, H,
      (long long)MC, (long long)CH, (long long)MH, 1.f, 0, 0);

  // vp [B][T][H] -> vpT [B][H][T]
  transpose64<<<dim3(T / 64, H / 64, B), 256, 0, stream>>>(
      qkvp + 2 * MH, vpT, T, H);

  // S = qp*kp^T / 32 (bf16 out), causal tile skip
  gemm_bt<128, 1><<<dim3(T / 128, T / 128, B), 512, 0, stream>>>(
      qkvp, qkvp + MH, Sb, H, H, H, T,
      (long long)T * H, (long long)T * H, (long long)T * T, 0.03125f, 1, 0);

  softmax_causal<<<dim3(B * T), 256, 0, stream>>>(Sb, T);

  // out = P * vpT^T  (K limited to m0+128: P is zero above diagonal)
  gemm_bt<128, 0><<<dim3(T / 128, H / 128, B), 512, 0, stream>>>(
      Sb, vpT, out, T, T, T, H,
      (long long)T * T, (long long)H * T, (long long)T * H, 1.f, 0, 1);
}

// Round 4
// 359.564 us; speedup vs baseline: 1.1120x; 1.0082x over previous
//
#include <hip/hip_runtime.h>
#include <stdint.h>

typedef unsigned short u16;
typedef __attribute__((ext_vector_type(8))) short short8;
typedef __attribute__((ext_vector_type(8))) u16 ushort8;
typedef __attribute__((ext_vector_type(4))) u16 u16x4;
typedef __attribute__((ext_vector_type(4))) float floatx4;

__device__ __forceinline__ u16 f2bf(float f) {
  union { float f; unsigned u; } c; c.f = f;
  unsigned u = c.u;
  return (u16)((u + 0x7fffu + ((u >> 16) & 1u)) >> 16);
}
__device__ __forceinline__ float bf2f(u16 h) {
  union { unsigned u; float f; } c; c.u = (unsigned)h << 16;
  return c.f;
}

// async global->LDS, 16 bytes per lane; LDS dest must be lane-contiguous.
__device__ __forceinline__ void async16(const u16* g, u16* l) {
  auto* gp = reinterpret_cast<const __attribute__((address_space(1))) uint32_t*>(
      reinterpret_cast<uintptr_t>(g));
  auto* lp = reinterpret_cast<__attribute__((address_space(3))) uint32_t*>(
      reinterpret_cast<uintptr_t>(l));
  __builtin_amdgcn_global_load_lds(gp, lp, 16, 0, 0);
}

// ---------------------------------------------------------------------------
// C = A * B^T.  A: [M][K] bf16 row-major (lda), B: [N][K] bf16 row-major (ldb).
// 256 threads = 4 waves, 128x128 tile, per-wave 64x64 (m97 shape).
// LDS XOR swizzle: 16B segment s of row r stored at phys seg s ^ ((r>>1)&3)
// -> ds_read_b128 fragment reads are 2-way-per-bank (free), not 8-way.
// causal_skip: skip tiles fully above diagonal. causal_klimit: K < m0+128.
// vpt: blockIdx.z==2 writes bf16 C transposed into vpC as [B=4][H=1024][T=2048]
// (m encodes b*2048+t), used to produce vp^T directly from the projection.
// ---------------------------------------------------------------------------
template <int OUT_BF16>
__global__ __launch_bounds__(256) void gemm_bt(
    const u16* __restrict__ A, const u16* __restrict__ B, void* __restrict__ Cv,
    int K, int lda, int ldb, int ldc,
    long long sA, long long sB, long long sC,
    float scale, int causal_skip, int causal_klimit,
    int vpt, u16* __restrict__ vpC) {
  const int m0 = blockIdx.x * 128;
  const int n0 = blockIdx.y * 128;
  if (causal_skip && n0 >= m0 + 128) return;
  A += (size_t)blockIdx.z * sA;
  B += (size_t)blockIdx.z * sB;

  __shared__ u16 As[128 * 32];
  __shared__ u16 Bs[128 * 32];

  const int tid = threadIdx.x;
  const int lane = tid & 63;
  const int wid = tid >> 6;
  const int wm = (wid & 1) * 64;
  const int wn = (wid >> 1) * 64;
  const int fr = lane & 15;   // m/n within 16x16 frag
  const int fq = lane >> 4;   // logical k-segment

  floatx4 acc[4][4] = {};

  int kt_end = K >> 5;
  if (causal_klimit) {
    int lim = (m0 >> 5) + 4;
    if (lim < kt_end) kt_end = lim;
  }

  const int rowi = tid >> 2;                       // 0..63
  const int segi = tid & 3;                        // physical 16B seg
  const int sgz = segi ^ ((rowi >> 1) & 3);        // logical seg to fetch
  const u16* gA = A + (size_t)(m0 + rowi) * lda + sgz * 8;
  const u16* gB = B + (size_t)(n0 + rowi) * ldb + sgz * 8;
  u16* lA = &As[tid * 8];
  u16* lB = &Bs[tid * 8];

  // fragment read addresses (swizzled), hoisted
  const u16* rdA[4];
  const u16* rdB[4];
#pragma unroll
  for (int i = 0; i < 4; ++i) {
    int ra = wm + i * 16 + fr;
    rdA[i] = &As[ra * 32 + (fq ^ ((ra >> 1) & 3)) * 8];
    int rb = wn + i * 16 + fr;
    rdB[i] = &Bs[rb * 32 + (fq ^ ((rb >> 1) & 3)) * 8];
  }

  for (int kt = 0; kt < kt_end; ++kt) {
    const int k0 = kt << 5;
    async16(gA + k0, lA);
    async16(gA + k0 + (size_t)64 * lda, lA + 2048);
    async16(gB + k0, lB);
    async16(gB + k0 + (size_t)64 * ldb, lB + 2048);
    __builtin_amdgcn_s_waitcnt(0);
    __syncthreads();

    short8 av[4], bv[4];
#pragma unroll
    for (int i = 0; i < 4; ++i) av[i] = *(const short8*)rdA[i];
#pragma unroll
    for (int j = 0; j < 4; ++j) bv[j] = *(const short8*)rdB[j];

#pragma unroll
    for (int i = 0; i < 4; ++i)
#pragma unroll
      for (int j = 0; j < 4; ++j)
        acc[i][j] = __builtin_amdgcn_mfma_f32_16x16x32_bf16(av[i], bv[j],
                                                            acc[i][j], 0, 0, 0);
    __syncthreads();
  }

  // Epilogue. C/D layout: col = lane&15 (=fr), row = fq*4 + reg.
  if (vpt && blockIdx.z == 2) {
    // write transposed: vpC[b][n][t], b = m>>11, t = m&2047 (T=2048, H=1024)
#pragma unroll
    for (int i = 0; i < 4; ++i) {
      const int m = m0 + wm + i * 16 + fq * 4;
      const int b = m >> 11, t = m & 2047;
#pragma unroll
      for (int j = 0; j < 4; ++j) {
        const int n = n0 + wn + j * 16 + fr;
        u16x4 o;
#pragma unroll
        for (int r = 0; r < 4; ++r) o[r] = f2bf(acc[i][j][r]);
        *(u16x4*)&vpC[(size_t)b * 2097152 + (size_t)n * 2048 + t] = o;
      }
    }
    return;
  }
  if (OUT_BF16) {
    u16* C = (u16*)Cv + (size_t)blockIdx.z * sC;
#pragma unroll
    for (int i = 0; i < 4; ++i) {
      const int m = m0 + wm + i * 16 + fq * 4;
#pragma unroll
      for (int j = 0; j < 4; ++j) {
        const int n = n0 + wn + j * 16 + fr;
#pragma unroll
        for (int r = 0; r < 4; ++r)
          C[(size_t)(m + r) * ldc + n] = f2bf(acc[i][j][r] * scale);
      }
    }
  } else {
    float* C = (float*)Cv + (size_t)blockIdx.z * sC;
#pragma unroll
    for (int i = 0; i < 4; ++i) {
      const int m = m0 + wm + i * 16 + fq * 4;
#pragma unroll
      for (int j = 0; j < 4; ++j) {
        const int n = n0 + wn + j * 16 + fr;
#pragma unroll
        for (int r = 0; r < 4; ++r)
          C[(size_t)(m + r) * ldc + n] = acc[i][j][r] * scale;
      }
    }
  }
}

// fp32 -> bf16 cast for q,k,v in one dispatch (blockIdx.y selects source)
__global__ __launch_bounds__(256) void cast3(
    const float* __restrict__ q, const float* __restrict__ k,
    const float* __restrict__ v, u16* __restrict__ out, int n8) {
  int i = blockIdx.x * 256 + threadIdx.x;
  if (i >= n8) return;
  const float* src = blockIdx.y == 0 ? q : (blockIdx.y == 1 ? k : v);
  u16* dst = out + (size_t)blockIdx.y * n8 * 8;
  floatx4 a = ((const floatx4*)src)[i * 2];
  floatx4 b = ((const floatx4*)src)[i * 2 + 1];
  ushort8 o;
#pragma unroll
  for (int j = 0; j < 4; ++j) { o[j] = f2bf(a[j]); o[4 + j] = f2bf(b[j]); }
  ((ushort8*)dst)[i] = o;
}

// fp32 [R][C] -> bf16 [C][R] transpose+cast, 64x64 tiles; z picks (Wq,Wk,Wq)
__global__ __launch_bounds__(256) void transpose_castW(
    const float* __restrict__ Wq, const float* __restrict__ Wk,
    u16* __restrict__ out, int R, int C) {
  __shared__ u16 tile[64][72];
  const float* in = (blockIdx.z == 1) ? Wk : Wq;
  u16* dst = out + (size_t)blockIdx.z * R * C;
  const int r0 = blockIdx.x * 64;
  const int c0 = blockIdx.y * 64;
  const int tid = threadIdx.x;
#pragma unroll
  for (int rnd = 0; rnd < 2; ++rnd) {
    int e = rnd * 256 + tid;
    int rr = e >> 3, seg = e & 7;
    const float* p = &in[(size_t)(r0 + rr) * C + c0 + seg * 8];
    floatx4 a = *(const floatx4*)p;
    floatx4 b = *(const floatx4*)(p + 4);
    u16* tp = &tile[rr][seg * 8];
#pragma unroll
    for (int j = 0; j < 4; ++j) { tp[j] = f2bf(a[j]); tp[4 + j] = f2bf(b[j]); }
  }
  __syncthreads();
#pragma unroll
  for (int rnd = 0; rnd < 2; ++rnd) {
    int e = rnd * 256 + tid;
    int cc = e >> 3, rseg = e & 7;
    ushort8 tv;
#pragma unroll
    for (int j = 0; j < 8; ++j) tv[j] = tile[rseg * 8 + j][cc];
    *(ushort8*)&dst[(size_t)(c0 + cc) * R + r0 + rseg * 8] = tv;
  }
}

// Causal row softmax, bf16 in-place. All reads complete before the sum-barrier;
// writes only after it -> in-place safe within the block's own row.
__global__ __launch_bounds__(256) void softmax_causal(u16* __restrict__ S,
                                                      int T) {
  const int row = blockIdx.x;
  const int t = row & (T - 1);
  const int len = t + 1;
  u16* srow = S + (size_t)row * T;
  const int tid = threadIdx.x;

  float vals[8];
  int cnt = 0;
  float mx = -1e30f;
  for (int i = tid; i < len; i += 256) {
    float v = bf2f(srow[i]);
    vals[cnt++] = v;
    mx = fmaxf(mx, v);
  }
  __shared__ float red[4];
#pragma unroll
  for (int o = 32; o > 0; o >>= 1) mx = fmaxf(mx, __shfl_down(mx, o, 64));
  if ((tid & 63) == 0) red[tid >> 6] = mx;
  __syncthreads();
  mx = fmaxf(fmaxf(red[0], red[1]), fmaxf(red[2], red[3]));
  __syncthreads();

  float sum = 0.f;
  for (int c = 0; c < cnt; ++c) {
    vals[c] = __expf(vals[c] - mx);
    sum += vals[c];
  }
#pragma unroll
  for (int o = 32; o > 0; o >>= 1) sum += __shfl_down(sum, o, 64);
  if ((tid & 63) == 0) red[tid >> 6] = sum;
  __syncthreads();
  sum = red[0] + red[1] + red[2] + red[3];
  const float inv = 1.f / sum;

  int c = 0;
  for (int i = tid; i < len; i += 256) srow[i] = f2bf(vals[c++] * inv);
  for (int i = tid; i < T; i += 256)
    if (i >= len) srow[i] = 0;
}

extern "C" void kernel_launch(void* const* d_in, const int* in_sizes, int n_in,
                              void* d_out, int out_size, void* d_ws,
                              size_t ws_size, hipStream_t stream) {
  (void)in_sizes; (void)n_in; (void)out_size; (void)ws_size;
  const float* k  = (const float*)d_in[1];
  const float* q  = (const float*)d_in[2];
  const float* v  = (const float*)d_in[3];
  const float* Wk = (const float*)d_in[4];
  const float* Wq = (const float*)d_in[5];
  float* out = (float*)d_out;

  const int B = 4, T = 2048, C = 1024, H = 1024;
  const int M = B * T;  // 8192
  const size_t MC = (size_t)M * C, CH = (size_t)C * H, MH = (size_t)M * H;

  u16* qkv  = (u16*)d_ws;        // 3 slots [M][C] bf16 (q,k,v)        50 MB
  u16* WT   = qkv + 3 * MC;      // 3 slots [H][C] bf16 (Wq,Wk,Wq)      6 MB
  u16* qkvp = WT + 3 * CH;       // slot0 qp, slot1 kp [M][H]          34 MB
  u16* vpT  = qkvp + 2 * MH;     // [B][H][T] bf16 (vp^T, direct)      17 MB
  u16* Sb   = vpT + MH;          // [B][T][T] bf16 (S, then P)       33.5 MB

  const int n8 = (int)(MC / 8);
  cast3<<<dim3(n8 / 256, 3), 256, 0, stream>>>(q, k, v, qkv, n8);
  transpose_castW<<<dim3(C / 64, H / 64, 3), 256, 0, stream>>>(Wq, Wk, WT, C, H);

  // qp = q*Wq, kp = k*Wk, vp^T = (v*Wq)^T  (one batched dispatch, z=0..2)
  gemm_bt<1><<<dim3(M / 128, H / 128, 3), 256, 0, stream>>>(
      qkv, WT, qkvp, C, C, C, H,
      (long long)MC, (long long)CH, (long long)MH, 1.f, 0, 0, 1, vpT);

  // S = qp*kp^T / 32 (bf16 out), causal tile skip
  gemm_bt<1><<<dim3(T / 128, T / 128, B), 256, 0, stream>>>(
      qkvp, qkvp + MH, Sb, H, H, H, T,
      (long long)T * H, (long long)T * H, (long long)T * T,
      0.03125f, 1, 0, 0, nullptr);

  softmax_causal<<<dim3(B * T), 256, 0, stream>>>(Sb, T);

  // out = P * vpT^T  (K limited to m0+128: P is zero above diagonal)
  gemm_bt<0><<<dim3(T / 128, H / 128, B), 256, 0, stream>>>(
      Sb, vpT, out, T, T, T, H,
      (long long)T * T, (long long)H * T, (long long)T * H,
      1.f, 0, 1, 0, nullptr);
}

// Round 5
// 332.067 us; speedup vs baseline: 1.2041x; 1.0828x over previous
//
#include <hip/hip_runtime.h>
#include <stdint.h>
#include <math.h>

typedef unsigned short u16;
typedef __attribute__((ext_vector_type(8))) short short8;
typedef __attribute__((ext_vector_type(8))) u16 ushort8;
typedef __attribute__((ext_vector_type(4))) u16 u16x4;
typedef __attribute__((ext_vector_type(4))) float floatx4;

__device__ __forceinline__ u16 f2bf(float f) {
  union { float f; unsigned u; } c; c.f = f;
  unsigned u = c.u;
  return (u16)((u + 0x7fffu + ((u >> 16) & 1u)) >> 16);
}
__device__ __forceinline__ float bf2f(u16 h) {
  union { unsigned u; float f; } c; c.u = (unsigned)h << 16;
  return c.f;
}

// async global->LDS, 16 bytes per lane; LDS dest must be lane-contiguous.
__device__ __forceinline__ void async16(const u16* g, u16* l) {
  auto* gp = reinterpret_cast<const __attribute__((address_space(1))) uint32_t*>(
      reinterpret_cast<uintptr_t>(g));
  auto* lp = reinterpret_cast<__attribute__((address_space(3))) uint32_t*>(
      reinterpret_cast<uintptr_t>(l));
  __builtin_amdgcn_global_load_lds(gp, lp, 16, 0, 0);
}

// s_waitcnt immediates (gfx9 encoding): vmcnt[3:0] | expcnt<<4 | lgkmcnt<<8
#define WAIT_VM4 0xF74  // vmcnt(4): wait until <=4 vmem ops outstanding
#define WAIT_VM0 0xF70  // vmcnt(0)

// ---------------------------------------------------------------------------
// C = A * B^T.  A: [M][K] bf16 row-major (lda), B: [N][K] bf16 row-major (ldb).
// 256 threads = 4 waves, 128x128 tile, per-wave 64x64.
// Double-buffered LDS + vmcnt(4) pipeline: tile k+1's global_load_lds stays in
// flight across the barrier while tile k computes (AITER-style; no
// __syncthreads -> no compiler vmcnt(0) drain).
// LDS XOR swizzle: 16B seg s of row r at phys seg s^((r>>1)&3) -> conflict-free.
// tri_grid: blockIdx.x enumerates lower-triangle tiles (S gemm).
// rev_m: reverse m-tile order so heavy causal_klimit blocks launch first.
// vpt: z==2 writes C transposed as [4][1024][2048] (vp^T direct).
// ---------------------------------------------------------------------------
template <int OUT_BF16>
__global__ __launch_bounds__(256) void gemm_bt(
    const u16* __restrict__ A, const u16* __restrict__ B, void* __restrict__ Cv,
    int K, int lda, int ldb, int ldc,
    long long sA, long long sB, long long sC,
    float scale, int tri_grid, int causal_klimit, int rev_m,
    int vpt, u16* __restrict__ vpC) {
  int bm, bn;
  if (tri_grid) {
    const int bx = blockIdx.x;
    int i = (int)((sqrtf(8.f * bx + 1.f) - 1.f) * 0.5f);
    while ((i + 1) * (i + 2) / 2 <= bx) ++i;
    while (i * (i + 1) / 2 > bx) --i;
    bm = i;
    bn = bx - i * (i + 1) / 2;
  } else {
    bm = rev_m ? ((int)gridDim.x - 1 - (int)blockIdx.x) : (int)blockIdx.x;
    bn = blockIdx.y;
  }
  const int m0 = bm * 128;
  const int n0 = bn * 128;
  A += (size_t)blockIdx.z * sA;
  B += (size_t)blockIdx.z * sB;

  __shared__ u16 As[2][4096];
  __shared__ u16 Bs[2][4096];

  const int tid = threadIdx.x;
  const int lane = tid & 63;
  const int wid = tid >> 6;
  const int wm = (wid & 1) * 64;
  const int wn = (wid >> 1) * 64;
  const int fr = lane & 15;   // m/n within 16x16 frag
  const int fq = lane >> 4;   // logical k-segment

  floatx4 acc[4][4] = {};

  int kt_end = K >> 5;
  if (causal_klimit) {
    int lim = (m0 >> 5) + 4;
    if (lim < kt_end) kt_end = lim;
  }

  const int rowi = tid >> 2;                 // 0..63
  const int segi = tid & 3;                  // physical 16B seg
  const int sgz = segi ^ ((rowi >> 1) & 3);  // logical seg to fetch
  const u16* gA = A + (size_t)(m0 + rowi) * lda + sgz * 8;
  const u16* gB = B + (size_t)(n0 + rowi) * ldb + sgz * 8;

  // fragment read offsets (swizzled), within one 4096-elem buffer
  int offA[4], offB[4];
#pragma unroll
  for (int i = 0; i < 4; ++i) {
    int ra = wm + i * 16 + fr;
    offA[i] = ra * 32 + (fq ^ ((ra >> 1) & 3)) * 8;
    int rb = wn + i * 16 + fr;
    offB[i] = rb * 32 + (fq ^ ((rb >> 1) & 3)) * 8;
  }

  auto issue = [&](int kt) {
    const int k0 = kt << 5;
    const int odd = kt & 1;
    async16(gA + k0, &As[odd][tid * 8]);
    async16(gA + k0 + (size_t)64 * lda, &As[odd][tid * 8 + 2048]);
    async16(gB + k0, &Bs[odd][tid * 8]);
    async16(gB + k0 + (size_t)64 * ldb, &Bs[odd][tid * 8 + 2048]);
  };

  issue(0);
  for (int kt = 0; kt < kt_end; ++kt) {
    if (kt + 1 < kt_end) {
      issue(kt + 1);
      __builtin_amdgcn_s_waitcnt(WAIT_VM4);  // tile kt's 4 loads retired
    } else {
      __builtin_amdgcn_s_waitcnt(WAIT_VM0);
    }
    asm volatile("s_barrier" ::: "memory");

    const u16* ab = As[kt & 1];
    const u16* bb = Bs[kt & 1];
    short8 av[4], bv[4];
#pragma unroll
    for (int i = 0; i < 4; ++i) av[i] = *(const short8*)(ab + offA[i]);
#pragma unroll
    for (int j = 0; j < 4; ++j) bv[j] = *(const short8*)(bb + offB[j]);

#pragma unroll
    for (int i = 0; i < 4; ++i)
#pragma unroll
      for (int j = 0; j < 4; ++j)
        acc[i][j] = __builtin_amdgcn_mfma_f32_16x16x32_bf16(av[i], bv[j],
                                                            acc[i][j], 0, 0, 0);
    asm volatile("s_barrier" ::: "memory");  // readers done before overwrite
  }

  // Epilogue. C/D layout: col = lane&15 (=fr), row = fq*4 + reg.
  if (vpt && blockIdx.z == 2) {
    // write transposed: vpC[b][n][t], b = m>>11, t = m&2047 (T=2048, H=1024)
#pragma unroll
    for (int i = 0; i < 4; ++i) {
      const int m = m0 + wm + i * 16 + fq * 4;
      const int b = m >> 11, t = m & 2047;
#pragma unroll
      for (int j = 0; j < 4; ++j) {
        const int n = n0 + wn + j * 16 + fr;
        u16x4 o;
#pragma unroll
        for (int r = 0; r < 4; ++r) o[r] = f2bf(acc[i][j][r]);
        *(u16x4*)&vpC[(size_t)b * 2097152 + (size_t)n * 2048 + t] = o;
      }
    }
    return;
  }
  if (OUT_BF16) {
    u16* C = (u16*)Cv + (size_t)blockIdx.z * sC;
#pragma unroll
    for (int i = 0; i < 4; ++i) {
      const int m = m0 + wm + i * 16 + fq * 4;
#pragma unroll
      for (int j = 0; j < 4; ++j) {
        const int n = n0 + wn + j * 16 + fr;
#pragma unroll
        for (int r = 0; r < 4; ++r)
          C[(size_t)(m + r) * ldc + n] = f2bf(acc[i][j][r] * scale);
      }
    }
  } else {
    float* C = (float*)Cv + (size_t)blockIdx.z * sC;
#pragma unroll
    for (int i = 0; i < 4; ++i) {
      const int m = m0 + wm + i * 16 + fq * 4;
#pragma unroll
      for (int j = 0; j < 4; ++j) {
        const int n = n0 + wn + j * 16 + fr;
#pragma unroll
        for (int r = 0; r < 4; ++r)
          C[(size_t)(m + r) * ldc + n] = acc[i][j][r] * scale;
      }
    }
  }
}

// fp32 -> bf16 cast for q,k,v in one dispatch (blockIdx.y selects source)
__global__ __launch_bounds__(256) void cast3(
    const float* __restrict__ q, const float* __restrict__ k,
    const float* __restrict__ v, u16* __restrict__ out, int n8) {
  int i = blockIdx.x * 256 + threadIdx.x;
  if (i >= n8) return;
  const float* src = blockIdx.y == 0 ? q : (blockIdx.y == 1 ? k : v);
  u16* dst = out + (size_t)blockIdx.y * n8 * 8;
  floatx4 a = ((const floatx4*)src)[i * 2];
  floatx4 b = ((const floatx4*)src)[i * 2 + 1];
  ushort8 o;
#pragma unroll
  for (int j = 0; j < 4; ++j) { o[j] = f2bf(a[j]); o[4 + j] = f2bf(b[j]); }
  ((ushort8*)dst)[i] = o;
}

// fp32 [R][C] -> bf16 [C][R] transpose+cast, 64x64 tiles; z picks (Wq,Wk,Wq)
__global__ __launch_bounds__(256) void transpose_castW(
    const float* __restrict__ Wq, const float* __restrict__ Wk,
    u16* __restrict__ out, int R, int C) {
  __shared__ u16 tile[64][72];
  const float* in = (blockIdx.z == 1) ? Wk : Wq;
  u16* dst = out + (size_t)blockIdx.z * R * C;
  const int r0 = blockIdx.x * 64;
  const int c0 = blockIdx.y * 64;
  const int tid = threadIdx.x;
#pragma unroll
  for (int rnd = 0; rnd < 2; ++rnd) {
    int e = rnd * 256 + tid;
    int rr = e >> 3, seg = e & 7;
    const float* p = &in[(size_t)(r0 + rr) * C + c0 + seg * 8];
    floatx4 a = *(const floatx4*)p;
    floatx4 b = *(const floatx4*)(p + 4);
    u16* tp = &tile[rr][seg * 8];
#pragma unroll
    for (int j = 0; j < 4; ++j) { tp[j] = f2bf(a[j]); tp[4 + j] = f2bf(b[j]); }
  }
  __syncthreads();
#pragma unroll
  for (int rnd = 0; rnd < 2; ++rnd) {
    int e = rnd * 256 + tid;
    int cc = e >> 3, rseg = e & 7;
    ushort8 tv;
#pragma unroll
    for (int j = 0; j < 8; ++j) tv[j] = tile[rseg * 8 + j][cc];
    *(ushort8*)&dst[(size_t)(c0 + cc) * R + r0 + rseg * 8] = tv;
  }
}

// Causal row softmax, bf16 in-place. All reads complete before the sum-barrier;
// writes only after it -> in-place safe within the block's own row.
__global__ __launch_bounds__(256) void softmax_causal(u16* __restrict__ S,
                                                      int T) {
  const int row = blockIdx.x;
  const int t = row & (T - 1);
  const int len = t + 1;
  u16* srow = S + (size_t)row * T;
  const int tid = threadIdx.x;

  float vals[8];
  int cnt = 0;
  float mx = -1e30f;
  for (int i = tid; i < len; i += 256) {
    float v = bf2f(srow[i]);
    vals[cnt++] = v;
    mx = fmaxf(mx, v);
  }
  __shared__ float red[4];
#pragma unroll
  for (int o = 32; o > 0; o >>= 1) mx = fmaxf(mx, __shfl_down(mx, o, 64));
  if ((tid & 63) == 0) red[tid >> 6] = mx;
  __syncthreads();
  mx = fmaxf(fmaxf(red[0], red[1]), fmaxf(red[2], red[3]));
  __syncthreads();

  float sum = 0.f;
  for (int c = 0; c < cnt; ++c) {
    vals[c] = __expf(vals[c] - mx);
    sum += vals[c];
  }
#pragma unroll
  for (int o = 32; o > 0; o >>= 1) sum += __shfl_down(sum, o, 64);
  if ((tid & 63) == 0) red[tid >> 6] = sum;
  __syncthreads();
  sum = red[0] + red[1] + red[2] + red[3];
  const float inv = 1.f / sum;

  int c = 0;
  for (int i = tid; i < len; i += 256) srow[i] = f2bf(vals[c++] * inv);
  for (int i = tid; i < T; i += 256)
    if (i >= len) srow[i] = 0;
}

extern "C" void kernel_launch(void* const* d_in, const int* in_sizes, int n_in,
                              void* d_out, int out_size, void* d_ws,
                              size_t ws_size, hipStream_t stream) {
  (void)in_sizes; (void)n_in; (void)out_size; (void)ws_size;
  const float* k  = (const float*)d_in[1];
  const float* q  = (const float*)d_in[2];
  const float* v  = (const float*)d_in[3];
  const float* Wk = (const float*)d_in[4];
  const float* Wq = (const float*)d_in[5];
  float* out = (float*)d_out;

  const int B = 4, T = 2048, C = 1024, H = 1024;
  const int M = B * T;  // 8192
  const size_t MC = (size_t)M * C, CH = (size_t)C * H, MH = (size_t)M * H;

  u16* qkv  = (u16*)d_ws;        // 3 slots [M][C] bf16 (q,k,v)        50 MB
  u16* WT   = qkv + 3 * MC;      // 3 slots [H][C] bf16 (Wq,Wk,Wq)      6 MB
  u16* qkvp = WT + 3 * CH;       // slot0 qp, slot1 kp [M][H]          34 MB
  u16* vpT  = qkvp + 2 * MH;     // [B][H][T] bf16 (vp^T, direct)      17 MB
  u16* Sb   = vpT + MH;          // [B][T][T] bf16 (S, then P)       33.5 MB

  const int n8 = (int)(MC / 8);
  cast3<<<dim3(n8 / 256, 3), 256, 0, stream>>>(q, k, v, qkv, n8);
  transpose_castW<<<dim3(C / 64, H / 64, 3), 256, 0, stream>>>(Wq, Wk, WT, C, H);

  // qp = q*Wq, kp = k*Wk, vp^T = (v*Wq)^T  (one batched dispatch, z=0..2)
  gemm_bt<1><<<dim3(M / 128, H / 128, 3), 256, 0, stream>>>(
      qkv, WT, qkvp, C, C, C, H,
      (long long)MC, (long long)CH, (long long)MH, 1.f, 0, 0, 0, 1, vpT);

  // S = qp*kp^T / 32 (bf16 out), compact lower-triangle grid (136 tiles/batch)
  gemm_bt<1><<<dim3(136, 1, B), 256, 0, stream>>>(
      qkvp, qkvp + MH, Sb, H, H, H, T,
      (long long)T * H, (long long)T * H, (long long)T * T,
      0.03125f, 1, 0, 0, 0, nullptr);

  softmax_causal<<<dim3(B * T), 256, 0, stream>>>(Sb, T);

  // out = P * vpT^T (K limited to m0+128: P zero above diagonal), heavy-first
  gemm_bt<0><<<dim3(T / 128, H / 128, B), 256, 0, stream>>>(
      Sb, vpT, out, T, T, T, H,
      (long long)T * T, (long long)H * T, (long long)T * H,
      1.f, 0, 1, 1, 0, nullptr);
}